// Round 1
// baseline (192.651 us; speedup 1.0000x reference)
//
#include <hip/hip_runtime.h>

// ---------------------------------------------------------------------------
// BinaryConv2d via implicit GEMM on i8 MFMA (weights exactly +/-1 in i8;
// x quantized with scale 5.5/127).
//   A[o][k] = sign(W) in i8, k = (kh*3+kw)*128 + c   (M = 256, K = 1152)
//   B[k][s] = quant(x_pad) NHWC i8, s = n*3136+h*56+w (N = 100352)
// R4: 256x128 tile (o x s), 512 thr / 8 waves, double-buffered LDS (96 KB),
// counted-vmcnt 2-phase-per-K-tile pipeline (T3+T4) + setprio (T5) +
// bijective XCD chunk swizzle (T1). Lifted the (256,4) VGPR cap (spill risk).
// ---------------------------------------------------------------------------

typedef __attribute__((ext_vector_type(4))) float float4v;
typedef __attribute__((ext_vector_type(4))) int int4v;
typedef __attribute__((ext_vector_type(2))) unsigned long long ull2;

#define N_IMG 32
#define C_IN 128
#define HH 56
#define WW 56
#define O_CH 256
#define HP 58
#define WP 58
#define K_TOT 1152            // 9 * 128
#define S_IMG 3136            // 56*56
#define S_TOT (N_IMG * S_IMG) // 100352
#define OUT_IMG (O_CH * S_IMG)

#define QSTEP (5.5f / 127.0f)   // dequant scale
#define QINV (127.0f / 5.5f)    // quant scale

__device__ __forceinline__ signed char quant_i8(float f) {
  float v = f * QINV;
  v = fminf(fmaxf(v, -127.0f), 127.0f);
  return (signed char)__float2int_rn(v);
}

__device__ __forceinline__ void load_lds16(const void* g, void* l) {
  // 16B per lane; LDS dest = wave-uniform base + lane*16 (HW rule)
  __builtin_amdgcn_global_load_lds(
      (const __attribute__((address_space(1))) unsigned int*)g,
      (__attribute__((address_space(3))) unsigned int*)l,
      16, 0, 0);
}

// x (N,C,H,W) f32 -> x_pad (N,58,58,C) i8 (quantized), zero borders baked in.
// LDS transpose: xs[cc=c>>3][w][cl=c&7] i8, cc-stride 464 B (57*8 + 8 pad).
__global__ __launch_bounds__(256) void bconv_pad_kernel(
    const float* __restrict__ x, signed char* __restrict__ xpad) {
  __shared__ signed char xs[16 * 464];
  int hp = blockIdx.x; // 0..57
  int n = blockIdx.y;  // 0..31
  int tid = threadIdx.x;
  bool hborder = (hp == 0) | (hp == HP - 1);
  if (!hborder) {
    int h = hp - 1;
    const float* xb = x + ((long)n * C_IN) * S_IMG + h * WW;
    // 128 c * 14 float4 = 1792 items = 7 * 256
#pragma unroll
    for (int it = 0; it < 7; ++it) {
      int item = it * 256 + tid;
      int c = item / 14;
      int f4 = item - c * 14;
      float4v v = *(const float4v*)(xb + (long)c * S_IMG + f4 * 4);
      int cc = c >> 3, cl = c & 7;
#pragma unroll
      for (int j = 0; j < 4; ++j)
        xs[cc * 464 + (f4 * 4 + j) * 8 + cl] = quant_i8(v[j]);
    }
  }
  __syncthreads();
  // 58 wp * 8 chunks(16B) = 464 items; contiguous 16B/lane global stores.
  long obase = (((long)n * HP + hp) * WP) * C_IN;
#pragma unroll
  for (int r = 0; r < 2; ++r) {
    int item = r * 256 + tid;
    if (item < 464) {
      int wp = item >> 3;
      int ch = item & 7; // 16-channel chunk
      ull2 v;
      if (hborder | (wp == 0) | (wp == WP - 1)) {
        v = (ull2){0ull, 0ull};
      } else {
        unsigned long long a = *(const unsigned long long*)&xs[(2 * ch) * 464 + (wp - 1) * 8];
        unsigned long long b = *(const unsigned long long*)&xs[(2 * ch + 1) * 464 + (wp - 1) * 8];
        v = (ull2){a, b};
      }
      *(ull2*)&xpad[obase + (long)item * 16] = v;
    }
  }
}

// weight (O,C,3,3) f32 -> wA[o][k] i8 in {+1,-1}, k = (kh*3+kw)*128 + c
__global__ __launch_bounds__(256) void bconv_wprep_kernel(
    const float* __restrict__ w, signed char* __restrict__ wA) {
  int gid = blockIdx.x * 256 + threadIdx.x; // exact: 256*1152 threads
  int o = gid / K_TOT;
  int k = gid - o * K_TOT;
  int khw = k >> 7;
  int c = k & 127;
  float v = w[(o * C_IN + c) * 9 + khw];
  wA[gid] = (v >= 0.0f) ? (signed char)1 : (signed char)-1;
}

// ---------------------------------------------------------------------------
// GEMM: 256(o) x 128(s) tile, BK=128 i8 (one (kh,kw) c-block per K-tile,
// 9 K-tiles). 8 waves: wv&3 -> o quadrant (64), wv>>2 -> s half (64).
// Double-buffered LDS: A 2x32KB + B 2x16KB = 96KB -> 1 block/CU.
// Schedule per K-tile (2 phases, ki=0/1):
//   ph0: STAGE 3 (t+1) ; vmcnt(3) ; barrier ; ds_read ; setprio MFMA ; barrier
//   ph1: STAGE 3 (t+1) ; ds_read ; barrier ; setprio MFMA ; barrier
// vmcnt counted (3), drained to 0 only for the last tile.
// LDS rows: 128 B (8 x 16B chunks); chunk j of row r lives at slot j^(r&7).
// ---------------------------------------------------------------------------
__global__ __launch_bounds__(512, 1) void bconv_gemm_kernel(
    const signed char* __restrict__ wA, const signed char* __restrict__ xpad,
    const float* __restrict__ bias, float* __restrict__ out) {
  __shared__ signed char A_lds[2][256 * 128]; // [o_local][k] swizzled
  __shared__ signed char B_lds[2][128 * 128]; // [s_local][k] swizzled

  int tid = threadIdx.x;
  int wv = tid >> 6;
  int lane = tid & 63;

  // XCD chunk swizzle: 784 blocks, 784 % 8 == 0 -> simple bijective form.
  int bid = blockIdx.x;
  int sw_bid = (bid & 7) * (S_TOT / 128 / 8) + (bid >> 3);
  int s0 = sw_bid * 128;

  // Staging pointers. A: 2048 chunks (4/thread); B: 1024 chunks (2/thread).
  // LDS slot chunk = tid + i*512 holds global chunk jl ^ (row&7).
  const signed char* agp[4];
  const signed char* bgp[2];
#pragma unroll
  for (int i = 0; i < 4; ++i) {
    int chunk = tid + i * 512;
    int row = chunk >> 3;             // 0..255 (o)
    int jl = chunk & 7;               // LDS slot within row
    int ko = ((jl ^ (row & 7)) << 4); // swizzled k-offset, bytes
    agp[i] = wA + row * K_TOT + ko;
  }
#pragma unroll
  for (int i = 0; i < 2; ++i) {
    int chunk = tid + i * 512;
    int row = chunk >> 3; // 0..127 (s)
    int jl = chunk & 7;
    int ko = ((jl ^ (row & 7)) << 4);
    int sg = s0 + row;
    int nimg = sg / S_IMG;
    int simg = sg - nimg * S_IMG;
    int h = simg / WW;
    int w = simg - h * WW;
    bgp[i] = xpad + (((long)nimg * HP + h) * WP + w) * C_IN + ko;
  }

  int4v acc[4][4];
#pragma unroll
  for (int a = 0; a < 4; ++a)
#pragma unroll
    for (int b = 0; b < 4; ++b)
      acc[a][b] = (int4v){0, 0, 0, 0};

  int o_off = (wv & 3) << 6;
  int s_off = (wv >> 2) << 6;
  int fm = lane & 15;
  int q = lane >> 4;
  int swz0 = ((q ^ (fm & 7)) << 4); // byte offset of ki=0 chunk; ki=1 -> ^64

  // Prologue: stage K-tile 0 (kh=0, kw=0 -> both deltas 0).
  load_lds16(agp[0], &A_lds[0][0] + wv * 1024 + 0 * 8192);
  load_lds16(agp[1], &A_lds[0][0] + wv * 1024 + 1 * 8192);
  load_lds16(agp[2], &A_lds[0][0] + wv * 1024 + 2 * 8192);
  load_lds16(agp[3], &A_lds[0][0] + wv * 1024 + 3 * 8192);
  load_lds16(bgp[0], &B_lds[0][0] + wv * 1024 + 0 * 8192);
  load_lds16(bgp[1], &B_lds[0][0] + wv * 1024 + 1 * 8192);

  for (int t = 0; t < 9; ++t) {
    const signed char* Ab = &A_lds[t & 1][0];
    const signed char* Bb = &B_lds[t & 1][0];
    signed char* An = &A_lds[(t & 1) ^ 1][0];
    signed char* Bn = &B_lds[(t & 1) ^ 1][0];
    int kn = t + 1; // next K-tile = (kh,kw)
    int kh = kn / 3;
    int kw = kn - kh * 3;
    int aoffg = kn << 7;               // A byte delta for tile kn
    int boffg = (kh * WP + kw) * C_IN; // B byte delta for tile kn

    // ---------------- phase 0 (ki = 0) ----------------
    if (t < 8) {
      load_lds16(agp[0] + aoffg, An + wv * 1024 + 0 * 8192);
      load_lds16(agp[1] + aoffg, An + wv * 1024 + 1 * 8192);
      load_lds16(bgp[0] + boffg, Bn + wv * 1024 + 0 * 8192);
      // wait for the 6 loads of tile t (issued last tile); keep 3 in flight
      asm volatile("s_waitcnt vmcnt(3)" ::: "memory");
    } else {
      asm volatile("s_waitcnt vmcnt(0)" ::: "memory");
    }
    __builtin_amdgcn_s_barrier(); // tile-t LDS now valid for ALL waves
    {
      int4v af[4], bf[4];
#pragma unroll
      for (int i = 0; i < 4; ++i)
        af[i] = *(const int4v*)(Ab + (o_off + i * 16 + fm) * 128 + swz0);
#pragma unroll
      for (int i = 0; i < 4; ++i)
        bf[i] = *(const int4v*)(Bb + (s_off + i * 16 + fm) * 128 + swz0);
      __builtin_amdgcn_s_setprio(1);
#pragma unroll
      for (int io = 0; io < 4; ++io)
#pragma unroll
        for (int is = 0; is < 4; ++is)
          acc[io][is] = __builtin_amdgcn_mfma_i32_16x16x64_i8(
              af[io], bf[is], acc[io][is], 0, 0, 0);
      __builtin_amdgcn_s_setprio(0);
    }
    __builtin_amdgcn_s_barrier();

    // ---------------- phase 1 (ki = 1) ----------------
    if (t < 8) {
      load_lds16(agp[2] + aoffg, An + wv * 1024 + 2 * 8192);
      load_lds16(agp[3] + aoffg, An + wv * 1024 + 3 * 8192);
      load_lds16(bgp[1] + boffg, Bn + wv * 1024 + 1 * 8192);
    }
    {
      int4v af[4], bf[4];
      int sw1 = swz0 ^ 64;
#pragma unroll
      for (int i = 0; i < 4; ++i)
        af[i] = *(const int4v*)(Ab + (o_off + i * 16 + fm) * 128 + sw1);
#pragma unroll
      for (int i = 0; i < 4; ++i)
        bf[i] = *(const int4v*)(Bb + (s_off + i * 16 + fm) * 128 + sw1);
      __builtin_amdgcn_s_barrier();
      __builtin_amdgcn_s_setprio(1);
#pragma unroll
      for (int io = 0; io < 4; ++io)
#pragma unroll
        for (int is = 0; is < 4; ++is)
          acc[io][is] = __builtin_amdgcn_mfma_i32_16x16x64_i8(
              af[io], bf[is], acc[io][is], 0, 0, 0);
      __builtin_amdgcn_s_setprio(0);
    }
    __builtin_amdgcn_s_barrier(); // tile-t reads drained before t+1 STAGE
  }

  // Epilogue: D[row=o: q*4+reg][col=s: lane&15]; dequant + bias.
  float bco[4][4];
#pragma unroll
  for (int io = 0; io < 4; ++io)
#pragma unroll
    for (int r = 0; r < 4; ++r)
      bco[io][r] = bias[o_off + io * 16 + q * 4 + r];

#pragma unroll
  for (int is = 0; is < 4; ++is) {
    int sg = s0 + s_off + is * 16; // 16-aligned; 3136 % 16 == 0
    int nimg = sg / S_IMG;
    int simg = sg - nimg * S_IMG;
    float* ob = out + (long)nimg * OUT_IMG + simg + fm;
#pragma unroll
    for (int io = 0; io < 4; ++io) {
      int obch = o_off + io * 16 + q * 4;
#pragma unroll
      for (int r = 0; r < 4; ++r) {
        int o = obch + r;
        ob[(long)o * S_IMG] = (float)acc[io][is][r] * QSTEP + bco[io][r];
      }
    }
  }
}

extern "C" void kernel_launch(void* const* d_in, const int* in_sizes, int n_in,
                              void* d_out, int out_size, void* d_ws, size_t ws_size,
                              hipStream_t stream) {
  const float* x = (const float*)d_in[0];    // (32,128,56,56)
  const float* w = (const float*)d_in[1];    // (256,128,3,3)
  const float* bias = (const float*)d_in[2]; // (256,)
  float* out = (float*)d_out;                // (32,256,56,56)

  signed char* xpad = (signed char*)d_ws;                  // 32*58*58*128 = 13.5 MB
  signed char* wA = xpad + (size_t)N_IMG * HP * WP * C_IN; // 256*1152

  bconv_pad_kernel<<<dim3(HP, N_IMG), 256, 0, stream>>>(x, xpad);
  bconv_wprep_kernel<<<dim3((O_CH * K_TOT) / 256), 256, 0, stream>>>(w, wA);
  bconv_gemm_kernel<<<dim3(S_TOT / 128), 512, 0, stream>>>(wA, xpad, bias, out);
}

// Round 3
// 173.689 us; speedup vs baseline: 1.1092x; 1.1092x over previous
//
#include <hip/hip_runtime.h>

// ---------------------------------------------------------------------------
// BinaryConv2d via implicit GEMM on i8 MFMA (weights exactly +/-1 in i8;
// x quantized with scale 5.5/127).
//   A[o][k] = sign(W) in i8, k = (kh*3+kw)*128 + c   (M = 256, K = 1152)
//   B[k][s] = quant(x_pad) NHWC i8, s = n*3136+h*56+w (N = 100352)
// R5 (resubmit; broker timeout last round): 128x128 tile (R3's verified
// staging/fragment/epilogue algebra) with R4's pipeline: double-buffered LDS
// (64 KB -> 2 blocks/CU), one counted vmcnt(8) + 2 barriers per K-tile,
// 32-MFMA setprio cluster, bijective XCD chunk swizzle over flattened
// 1568-block grid. Fixes the 1-block/CU barrier stall + 784-block tail of R4
// (MfmaUtil 16.7%, Occupancy 16.3%).
// ---------------------------------------------------------------------------

typedef __attribute__((ext_vector_type(4))) float float4v;
typedef __attribute__((ext_vector_type(4))) int int4v;
typedef __attribute__((ext_vector_type(2))) unsigned long long ull2;

#define N_IMG 32
#define C_IN 128
#define HH 56
#define WW 56
#define O_CH 256
#define HP 58
#define WP 58
#define K_TOT 1152            // 9 * 128
#define S_IMG 3136            // 56*56
#define S_TOT (N_IMG * S_IMG) // 100352
#define OUT_IMG (O_CH * S_IMG)

#define QSTEP (5.5f / 127.0f)   // dequant scale
#define QINV (127.0f / 5.5f)    // quant scale

__device__ __forceinline__ signed char quant_i8(float f) {
  float v = f * QINV;
  v = fminf(fmaxf(v, -127.0f), 127.0f);
  return (signed char)__float2int_rn(v);
}

__device__ __forceinline__ void load_lds16(const void* g, void* l) {
  // 16B per lane; LDS dest = wave-uniform base + lane*16 (HW rule)
  __builtin_amdgcn_global_load_lds(
      (const __attribute__((address_space(1))) unsigned int*)g,
      (__attribute__((address_space(3))) unsigned int*)l,
      16, 0, 0);
}

// x (N,C,H,W) f32 -> x_pad (N,58,58,C) i8 (quantized), zero borders baked in.
// LDS transpose: xs[cc=c>>3][w][cl=c&7] i8, cc-stride 464 B (57*8 + 8 pad).
__global__ __launch_bounds__(256) void bconv_pad_kernel(
    const float* __restrict__ x, signed char* __restrict__ xpad) {
  __shared__ signed char xs[16 * 464];
  int hp = blockIdx.x; // 0..57
  int n = blockIdx.y;  // 0..31
  int tid = threadIdx.x;
  bool hborder = (hp == 0) | (hp == HP - 1);
  if (!hborder) {
    int h = hp - 1;
    const float* xb = x + ((long)n * C_IN) * S_IMG + h * WW;
    // 128 c * 14 float4 = 1792 items = 7 * 256
#pragma unroll
    for (int it = 0; it < 7; ++it) {
      int item = it * 256 + tid;
      int c = item / 14;
      int f4 = item - c * 14;
      float4v v = *(const float4v*)(xb + (long)c * S_IMG + f4 * 4);
      int cc = c >> 3, cl = c & 7;
#pragma unroll
      for (int j = 0; j < 4; ++j)
        xs[cc * 464 + (f4 * 4 + j) * 8 + cl] = quant_i8(v[j]);
    }
  }
  __syncthreads();
  // 58 wp * 8 chunks(16B) = 464 items; contiguous 16B/lane global stores.
  long obase = (((long)n * HP + hp) * WP) * C_IN;
#pragma unroll
  for (int r = 0; r < 2; ++r) {
    int item = r * 256 + tid;
    if (item < 464) {
      int wp = item >> 3;
      int ch = item & 7; // 16-channel chunk
      ull2 v;
      if (hborder | (wp == 0) | (wp == WP - 1)) {
        v = (ull2){0ull, 0ull};
      } else {
        unsigned long long a = *(const unsigned long long*)&xs[(2 * ch) * 464 + (wp - 1) * 8];
        unsigned long long b = *(const unsigned long long*)&xs[(2 * ch + 1) * 464 + (wp - 1) * 8];
        v = (ull2){a, b};
      }
      *(ull2*)&xpad[obase + (long)item * 16] = v;
    }
  }
}

// weight (O,C,3,3) f32 -> wA[o][k] i8 in {+1,-1}, k = (kh*3+kw)*128 + c
__global__ __launch_bounds__(256) void bconv_wprep_kernel(
    const float* __restrict__ w, signed char* __restrict__ wA) {
  int gid = blockIdx.x * 256 + threadIdx.x; // exact: 256*1152 threads
  int o = gid / K_TOT;
  int k = gid - o * K_TOT;
  int khw = k >> 7;
  int c = k & 127;
  float v = w[(o * C_IN + c) * 9 + khw];
  wA[gid] = (v >= 0.0f) ? (signed char)1 : (signed char)-1;
}

// ---------------------------------------------------------------------------
// GEMM: 128(o) x 128(s) tile, BK=128 i8 (one (kh,kw) c-block per K-tile,
// 9 K-tiles). 256 thr / 4 waves (2x2), per wave 64x64 out = 4x4 accs.
// Double-buffered LDS: (16+16) KB x 2 = 64 KB -> 2 blocks/CU.
// Per K-tile: STAGE 8 loads (t+1) ; vmcnt(8) ; barrier ; 16 ds_read_b128 ;
// setprio { 32 MFMA } ; barrier.  vmcnt counted, drained only on last tile.
// LDS rows: 128 B (8 x 16B chunks); chunk j of row r lives at slot j^(r&7).
// Grid: 1568 flattened (784 s-tiles x 2 o-tiles); bijective XCD chunk
// swizzle; o-pair adjacent so both readers of a B panel land on one XCD.
// ---------------------------------------------------------------------------
__global__ __launch_bounds__(256, 2) void bconv_gemm_kernel(
    const signed char* __restrict__ wA, const signed char* __restrict__ xpad,
    const float* __restrict__ bias, float* __restrict__ out) {
  __shared__ signed char A_lds[2][128 * 128]; // [o_local][k] swizzled
  __shared__ signed char B_lds[2][128 * 128]; // [s_local][k] swizzled

  int tid = threadIdx.x;
  int wv = tid >> 6;
  int lane = tid & 63;

  // 1568 blocks, 1568 % 8 == 0 -> simple bijective XCD chunk swizzle.
  int bid = blockIdx.x;
  int sw = (bid & 7) * (1568 / 8) + (bid >> 3);
  int s0 = (sw >> 1) * 128; // spatial tile (784)
  int o0 = (sw & 1) << 7;   // out-channel tile (2)

  // Staging: 1024 chunks per operand per tile; LDS slot chunk = tid + i*256
  // holds global chunk jg = jl ^ (row&7).  (R3-verified index algebra.)
  const signed char* agp[4];
  const signed char* bgp[4];
#pragma unroll
  for (int i = 0; i < 4; ++i) {
    int chunk = tid + i * 256;
    int row = chunk >> 3;             // 0..127
    int jl = chunk & 7;               // LDS slot within row
    int ko = ((jl ^ (row & 7)) << 4); // swizzled k-offset, bytes
    agp[i] = wA + (o0 + row) * K_TOT + ko;
    int sg = s0 + row;
    int nimg = sg / S_IMG;
    int simg = sg - nimg * S_IMG;
    int h = simg / WW;
    int w = simg - h * WW;
    bgp[i] = xpad + (((long)nimg * HP + h) * WP + w) * C_IN + ko;
  }

  int4v acc[4][4];
#pragma unroll
  for (int a = 0; a < 4; ++a)
#pragma unroll
    for (int b = 0; b < 4; ++b)
      acc[a][b] = (int4v){0, 0, 0, 0};

  int o_off = (wv & 1) << 6;
  int s_off = (wv >> 1) << 6;
  int fm = lane & 15;
  int q = lane >> 4;
  int swz0 = ((q ^ (fm & 7)) << 4); // byte offset of ki=0 chunk; ki=1 -> ^64

  // Prologue: stage K-tile 0 (kh=0, kw=0 -> both deltas 0) into buf 0.
#pragma unroll
  for (int i = 0; i < 4; ++i)
    load_lds16(agp[i], &A_lds[0][0] + wv * 1024 + i * 4096);
#pragma unroll
  for (int i = 0; i < 4; ++i)
    load_lds16(bgp[i], &B_lds[0][0] + wv * 1024 + i * 4096);

  for (int t = 0; t < 9; ++t) {
    const signed char* Ab = &A_lds[t & 1][0];
    const signed char* Bb = &B_lds[t & 1][0];
    signed char* An = &A_lds[(t & 1) ^ 1][0];
    signed char* Bn = &B_lds[(t & 1) ^ 1][0];

    if (t < 8) {
      int kn = t + 1; // next K-tile = (kh,kw)
      int kh = kn / 3;
      int kw = kn - kh * 3;
      int aoffg = kn << 7;               // A byte delta for tile kn
      int boffg = (kh * WP + kw) * C_IN; // B byte delta for tile kn
#pragma unroll
      for (int i = 0; i < 4; ++i)
        load_lds16(agp[i] + aoffg, An + wv * 1024 + i * 4096);
#pragma unroll
      for (int i = 0; i < 4; ++i)
        load_lds16(bgp[i] + boffg, Bn + wv * 1024 + i * 4096);
      // tile t's 8 loads (issued last iter) are the oldest; keep 8 in flight
      asm volatile("s_waitcnt vmcnt(8)" ::: "memory");
    } else {
      asm volatile("s_waitcnt vmcnt(0)" ::: "memory");
    }
    __builtin_amdgcn_s_barrier(); // tile-t LDS now valid for ALL waves

    int4v af[2][4], bf[2][4];
#pragma unroll
    for (int ki = 0; ki < 2; ++ki) {
      int sw_b = swz0 ^ (ki << 6);
#pragma unroll
      for (int i = 0; i < 4; ++i)
        af[ki][i] = *(const int4v*)(Ab + (o_off + i * 16 + fm) * 128 + sw_b);
#pragma unroll
      for (int i = 0; i < 4; ++i)
        bf[ki][i] = *(const int4v*)(Bb + (s_off + i * 16 + fm) * 128 + sw_b);
    }
    __builtin_amdgcn_s_setprio(1);
#pragma unroll
    for (int ki = 0; ki < 2; ++ki)
#pragma unroll
      for (int io = 0; io < 4; ++io)
#pragma unroll
        for (int is = 0; is < 4; ++is)
          acc[io][is] = __builtin_amdgcn_mfma_i32_16x16x64_i8(
              af[ki][io], bf[ki][is], acc[io][is], 0, 0, 0);
    __builtin_amdgcn_s_setprio(0);
    __builtin_amdgcn_s_barrier(); // all waves done reading buf[t&1]
  }

  // Epilogue: D[row=o: q*4+reg][col=s: lane&15]; dequant + bias.
  float bco[4][4];
#pragma unroll
  for (int io = 0; io < 4; ++io)
#pragma unroll
    for (int r = 0; r < 4; ++r)
      bco[io][r] = bias[o0 + o_off + io * 16 + q * 4 + r];

#pragma unroll
  for (int is = 0; is < 4; ++is) {
    int sg = s0 + s_off + is * 16; // 16-aligned; 3136 % 16 == 0
    int nimg = sg / S_IMG;
    int simg = sg - nimg * S_IMG;
    float* ob = out + (long)nimg * OUT_IMG + simg + fm;
#pragma unroll
    for (int io = 0; io < 4; ++io) {
      int obch = o0 + o_off + io * 16 + q * 4;
#pragma unroll
      for (int r = 0; r < 4; ++r) {
        int o = obch + r;
        ob[(long)o * S_IMG] = (float)acc[io][is][r] * QSTEP + bco[io][r];
      }
    }
  }
}

extern "C" void kernel_launch(void* const* d_in, const int* in_sizes, int n_in,
                              void* d_out, int out_size, void* d_ws, size_t ws_size,
                              hipStream_t stream) {
  const float* x = (const float*)d_in[0];    // (32,128,56,56)
  const float* w = (const float*)d_in[1];    // (256,128,3,3)
  const float* bias = (const float*)d_in[2]; // (256,)
  float* out = (float*)d_out;                // (32,256,56,56)

  signed char* xpad = (signed char*)d_ws;                  // 32*58*58*128 = 13.5 MB
  signed char* wA = xpad + (size_t)N_IMG * HP * WP * C_IN; // 256*1152

  bconv_pad_kernel<<<dim3(HP, N_IMG), 256, 0, stream>>>(x, xpad);
  bconv_wprep_kernel<<<dim3((O_CH * K_TOT) / 256), 256, 0, stream>>>(w, wA);
  bconv_gemm_kernel<<<dim3(S_TOT / 128 * 2), 256, 0, stream>>>(wA, xpad, bias, out);
}